// Round 11
// baseline (247.427 us; speedup 1.0000x reference)
//
#include <hip/hip_runtime.h>
#include <hip/hip_bf16.h>
#include <math.h>

#define B_ 8
#define N_ 384
#define F_ 64
#define H_ 128
#define LN_EPS 1e-5f
#define SEG_ 3            // j-range segments per i-row (TLP split)

typedef _Float16 f16;
typedef f16 f16x2 __attribute__((ext_vector_type(2)));
typedef f16 f16x4 __attribute__((ext_vector_type(4)));
typedef f16 f16x8 __attribute__((ext_vector_type(8)));
typedef float f32x4v __attribute__((ext_vector_type(4)));

static __device__ __forceinline__ f16x2 u2h(unsigned int u) {
    union { unsigned int u; f16x2 h; } c; c.u = u; return c.h;
}

// -------------------- setup kernels --------------------

// W2hT[n][k] = fp16( 0.5 * sum_f vW2[k,f] * sW1[f,n] )   (128x128, TRANSPOSED for MFMA A)
__global__ void k_prep_w2p(const float* __restrict__ vW2, const float* __restrict__ sW1,
                           unsigned short* __restrict__ W2hT) {
    int idx = blockIdx.x * 256 + threadIdx.x;   // 0..16383
    int k = idx >> 7, n = idx & 127;
    float acc = 0.f;
#pragma unroll
    for (int f = 0; f < F_; ++f) acc = fmaf(vW2[k * F_ + f], sW1[f * H_ + n], acc);
    f16 hv = (f16)(0.5f * acc);
    W2hT[n * H_ + k] = *reinterpret_cast<unsigned short*>(&hv);
}

// t[row][n] = sum_f (0.25*(in[row,f]+vb2[f])) * sW1[f,n] + 0.5*sb1[n]
__global__ void k_prep_t(const float* __restrict__ inp, const float* __restrict__ sW1,
                         const float* __restrict__ vb2, const float* __restrict__ sb1,
                         float* __restrict__ t) {
    int row = blockIdx.x;
    int n = threadIdx.x;
    float acc = 0.f;
#pragma unroll
    for (int f = 0; f < F_; ++f)
        acc = fmaf(0.25f * (inp[row * F_ + f] + vb2[f]), sW1[f * H_ + n], acc);
    t[row * H_ + n] = acc + 0.5f * sb1[n];
}

// Algebraic-LN coefficients: centered ca/cb/cc (·vg) as packed f16 (k_scores) and
// fp32 (k_x), + 6 covariance scalars.
__global__ void k_prep_coeff(const float* __restrict__ vW1, const float* __restrict__ vb1,
                             const float* __restrict__ vg, const float* __restrict__ vbeta,
                             unsigned int* __restrict__ coeffP, float* __restrict__ scal,
                             float* __restrict__ coeffF) {
    __shared__ float red[128];
    __shared__ float caS[128], cbS[128], ccS[128];
    const int d = threadIdx.x;   // 128
    float a = vW1[d], bb = vW1[H_ + d], c = vb1[d];

    float mA, mB, mC, Saa, Sbb, Scc, Sab, Sac, Sbc;
    float ca, cb, cc;
#define BMEAN(OUT, VAL)                                                  \
    red[d] = (VAL); __syncthreads();                                     \
    for (int st = 64; st > 0; st >>= 1) {                                \
        if (d < st) red[d] += red[d + st];                               \
        __syncthreads();                                                 \
    }                                                                    \
    OUT = red[0] * (1.f / 128.f); __syncthreads();

    BMEAN(mA, a); BMEAN(mB, bb); BMEAN(mC, c);
    ca = a - mA; cb = bb - mB; cc = c - mC;
    caS[d] = ca * vg[d]; cbS[d] = cb * vg[d]; ccS[d] = cc * vg[d];
    BMEAN(Saa, ca * ca); BMEAN(Sbb, cb * cb); BMEAN(Scc, cc * cc);
    BMEAN(Sab, ca * cb); BMEAN(Sac, ca * cc); BMEAN(Sbc, cb * cc);
#undef BMEAN
    __syncthreads();
    coeffF[d] = caS[d]; coeffF[128 + d] = cbS[d]; coeffF[256 + d] = ccS[d];
    if (d < 64) {
        int d0 = 2 * d;
        union { f16x2 h; unsigned int u; } cv;
        cv.h = (f16x2){(f16)caS[d0], (f16)caS[d0 + 1]};   coeffP[d]       = cv.u;
        cv.h = (f16x2){(f16)cbS[d0], (f16)cbS[d0 + 1]};   coeffP[64 + d]  = cv.u;
        cv.h = (f16x2){(f16)ccS[d0], (f16)ccS[d0 + 1]};   coeffP[128 + d] = cv.u;
        cv.h = (f16x2){(f16)vbeta[d0], (f16)vbeta[d0 + 1]}; coeffP[192 + d] = cv.u;
    }
    if (d == 0) {
        scal[0] = Saa; scal[1] = Sbb; scal[2] = Scc;
        scal[3] = Sab; scal[4] = Sac; scal[5] = Sbc;
    }
}

// -------------------- phase 1: scores (pipelined, SEG-split for TLP) --------------------
// blockIdx.x = ib*SEG_+seg: wave w owns i-row ib*4+w, j-tiles [seg*8, seg*8+8).
// Grid 2304 blocks (9/CU queued, ~3 resident) vs 768 before — the R10 occupancy fix.
// Per-segment online (m,s) stats -> rowmaxS/rowsumS[seg]; k_gred combines.
// __launch_bounds__(256) only — min-waves arg caps VGPR at 256/arg => spills (R5/R6).
__global__ __launch_bounds__(256) void k_scores(
    const float* __restrict__ pos, const unsigned int* __restrict__ coeffP,
    const float* __restrict__ scal, const unsigned short* __restrict__ W2hT,
    const float* __restrict__ t, const float* __restrict__ sW2,
    const float* __restrict__ sb2, float* __restrict__ scores,
    float* __restrict__ rowmaxS, float* __restrict__ rowsumS) {
    __shared__ __align__(16) char smem[36864];

    const int tid = threadIdx.x;
    const int b = blockIdx.y;
    const int w = tid >> 6, lane = tid & 63;
    const int seg = blockIdx.x % SEG_;
    const int i = (blockIdx.x / SEG_) * 4 + w;
    const int jt0 = seg * 8;
    const int ln = lane & 15, h4 = lane >> 4;

    char* rht0 = smem + w * 8192;
    char* rht1 = rht0 + 4096;
    char* tiS = smem + 32768 + w * 512;
    char* swS = smem + 34816 + w * 512;

    if (lane < 32) {
        *(float4*)(tiS + lane * 16) = *(const float4*)(t + (size_t)(b * N_ + i) * H_ + lane * 4);
        *(float4*)(swS + lane * 16) = *(const float4*)(sW2 + lane * 4);
    }

    // A-fragments resident (128 VGPR)
    f16x8 aF[8][4];
#pragma unroll
    for (int mf = 0; mf < 8; ++mf)
#pragma unroll
        for (int kc = 0; kc < 4; ++kc)
            aF[mf][kc] = *(const f16x8*)(W2hT + (mf * 16 + ln) * H_ + kc * 32 + h4 * 8);

    const int lA = lane & 7;
    const uint4 cagA = *(const uint4*)(coeffP + lA * 8);
    const uint4 cagB = *(const uint4*)(coeffP + lA * 8 + 4);
    const uint4 cbgA = *(const uint4*)(coeffP + 64 + lA * 8);
    const uint4 cbgB = *(const uint4*)(coeffP + 64 + lA * 8 + 4);
    const uint4 ccgA = *(const uint4*)(coeffP + 128 + lA * 8);
    const uint4 ccgB = *(const uint4*)(coeffP + 128 + lA * 8 + 4);
    const uint4 vbA  = *(const uint4*)(coeffP + 192 + lA * 8);
    const uint4 vbB  = *(const uint4*)(coeffP + 192 + lA * 8 + 4);

    const float Saa = scal[0], Sbb = scal[1], Scc = scal[2];
    const float Sab = scal[3], Sac = scal[4], Sbc = scal[5];
    const float sb2v = sb2[0];

    const float* pi = pos + (size_t)(b * N_ + i) * 3;
    const float ax = pi[0], ay = pi[1], az = pi[2];
    const int pA8 = lane >> 3;

    float* scoreRow = scores + (size_t)(b * N_ + i) * N_;

    float m_run = -1e30f, s_run = 0.f;

    auto prefPos = [&](int jt, float& b0x, float& b0y, float& b0z,
                       float& b1x, float& b1y, float& b1z) {
        const float* pj0 = pos + (size_t)(b * N_ + jt * 16 + pA8) * 3;
        const float* pj1 = pj0 + 24;
        b0x = pj0[0]; b0y = pj0[1]; b0z = pj0[2];
        b1x = pj1[0]; b1y = pj1[1]; b1z = pj1[2];
    };

    auto accInit = [&](f32x4v (&acc)[8], int jt) {
        const float* tjB = t + (size_t)(b * N_ + jt * 16 + ln) * H_ + h4 * 4;
#pragma unroll
        for (int mf = 0; mf < 8; ++mf) {
            float4 tiv = *(const float4*)(tiS + mf * 64 + h4 * 16);
            float4 tj = *(const float4*)(tjB + mf * 16);
            acc[mf][0] = tiv.x + tj.x;
            acc[mf][1] = tiv.y + tj.y;
            acc[mf][2] = tiv.z + tj.z;
            acc[mf][3] = tiv.w + tj.w;
        }
    };

    auto phaseApass = [&](char* buf, int q, float bx, float by, float bz) {
        const int pq = q * 8 + pA8;
        float dotv = ax * bx + ay * by + az * bz;
        float cx = ay * bz - az * by;
        float cy = az * bx - ax * bz;
        float cz = ax * by - ay * bx;
        float cns = cx * cx + cy * cy + cz * cz;
        float cn = sqrtf(cns);
        float var = Saa * dotv * dotv + Sbb * cns + Scc +
                    2.f * (Sab * dotv * cn + Sac * dotv + Sbc * cn);
        float rstd = rsqrtf(var + LN_EPS);
        f16 d2 = (f16)(dotv * rstd), c2 = (f16)(cn * rstd), r2 = (f16)rstd;
        f16x2 D2 = {d2, d2}, C2 = {c2, c2}, R2 = {r2, r2};
        const f16x2 Z = {(f16)0.f, (f16)0.f};

        f16x2 vp0 = __builtin_elementwise_max(D2 * u2h(cagA.x) + (C2 * u2h(cbgA.x) + (R2 * u2h(ccgA.x) + u2h(vbA.x))), Z);
        f16x2 vp1 = __builtin_elementwise_max(D2 * u2h(cagA.y) + (C2 * u2h(cbgA.y) + (R2 * u2h(ccgA.y) + u2h(vbA.y))), Z);
        f16x2 vp2 = __builtin_elementwise_max(D2 * u2h(cagA.z) + (C2 * u2h(cbgA.z) + (R2 * u2h(ccgA.z) + u2h(vbA.z))), Z);
        f16x2 vp3 = __builtin_elementwise_max(D2 * u2h(cagA.w) + (C2 * u2h(cbgA.w) + (R2 * u2h(ccgA.w) + u2h(vbA.w))), Z);
        f16x2 vp4 = __builtin_elementwise_max(D2 * u2h(cagB.x) + (C2 * u2h(cbgB.x) + (R2 * u2h(ccgB.x) + u2h(vbB.x))), Z);
        f16x2 vp5 = __builtin_elementwise_max(D2 * u2h(cagB.y) + (C2 * u2h(cbgB.y) + (R2 * u2h(ccgB.y) + u2h(vbB.y))), Z);
        f16x2 vp6 = __builtin_elementwise_max(D2 * u2h(cagB.z) + (C2 * u2h(cbgB.z) + (R2 * u2h(ccgB.z) + u2h(vbB.z))), Z);
        f16x2 vp7 = __builtin_elementwise_max(D2 * u2h(cagB.w) + (C2 * u2h(cbgB.w) + (R2 * u2h(ccgB.w) + u2h(vbB.w))), Z);

        f16x4 q0 = __builtin_shufflevector(vp0, vp1, 0, 1, 2, 3);
        f16x4 q1 = __builtin_shufflevector(vp2, vp3, 0, 1, 2, 3);
        f16x4 q2 = __builtin_shufflevector(vp4, vp5, 0, 1, 2, 3);
        f16x4 q3 = __builtin_shufflevector(vp6, vp7, 0, 1, 2, 3);
        f16x8 o0 = __builtin_shufflevector(q0, q1, 0, 1, 2, 3, 4, 5, 6, 7);
        f16x8 o1 = __builtin_shufflevector(q2, q3, 0, 1, 2, 3, 4, 5, 6, 7);

        const int rb = pq * 256, sw = (pq & 7) << 4;
        *(f16x8*)(buf + rb + ((lA * 32) ^ sw)) = o0;
        *(f16x8*)(buf + rb + ((lA * 32 + 16) ^ sw)) = o1;
    };

    auto gemm = [&](f32x4v (&acc)[8], char* buf) {
#pragma unroll
        for (int kc = 0; kc < 4; ++kc) {
            f16x8 bF = *(const f16x8*)(buf + ln * 256 + ((kc * 64 + h4 * 16) ^ ((ln & 7) << 4)));
#pragma unroll
            for (int mf = 0; mf < 8; ++mf)
                acc[mf] = __builtin_amdgcn_mfma_f32_16x16x32_f16(aF[mf][kc], bF, acc[mf], 0, 0, 0);
        }
    };

    auto phaseC = [&](f32x4v (&acc)[8], int jt) {
        float part = 0.f;
#pragma unroll
        for (int mf = 0; mf < 8; ++mf) {
            float4 swv = *(const float4*)(swS + mf * 64 + h4 * 16);
            part += fmaxf(acc[mf][0], 0.f) * swv.x;
            part += fmaxf(acc[mf][1], 0.f) * swv.y;
            part += fmaxf(acc[mf][2], 0.f) * swv.z;
            part += fmaxf(acc[mf][3], 0.f) * swv.w;
        }
        part += __shfl_xor(part, 16);
        part += __shfl_xor(part, 32);
        float sc = part + sb2v;
        if (h4 == 0) scoreRow[jt * 16 + ln] = sc;
        float mn = fmaxf(m_run, sc);
        s_run = s_run * expf(m_run - mn) + expf(sc - mn);
        m_run = mn;
    };

    f32x4v accP[8], accQ[8];
    float A0x, A0y, A0z, A1x, A1y, A1z;
    float B0x, B0y, B0z, B1x, B1y, B1z;

    // prologue: tile jt0 staged
    prefPos(jt0, A0x, A0y, A0z, A1x, A1y, A1z);
    accInit(accP, jt0);
    phaseApass(rht0, 0, A0x, A0y, A0z);
    phaseApass(rht0, 1, A1x, A1y, A1z);

#pragma unroll 1
    for (int jt = jt0; jt < jt0 + 8; jt += 2) {
        const int j1 = jt + 1;
        const int j2 = (jt + 2 < jt0 + 8) ? (jt + 2) : (jt0 + 7);   // clamp: last stage dead
        prefPos(j1, B0x, B0y, B0z, B1x, B1y, B1z);
        accInit(accQ, j1);
        gemm(accP, rht0);
        phaseApass(rht1, 0, B0x, B0y, B0z);
        phaseApass(rht1, 1, B1x, B1y, B1z);
        phaseC(accP, jt);
        prefPos(j2, A0x, A0y, A0z, A1x, A1y, A1z);
        accInit(accP, j2);
        gemm(accQ, rht1);
        phaseApass(rht0, 0, A0x, A0y, A0z);
        phaseApass(rht0, 1, A1x, A1y, A1z);
        phaseC(accQ, j1);
    }

    // row-stat reduce across ln (h4 replicas identical), fixed shuffle tree
#pragma unroll
    for (int d = 1; d < 16; d <<= 1) {
        float mo = __shfl_xor(m_run, d);
        float so = __shfl_xor(s_run, d);
        float mn = fmaxf(m_run, mo);
        s_run = s_run * expf(m_run - mn) + so * expf(mo - mn);
        m_run = mn;
    }
    if (lane == 0) {
        rowmaxS[seg * B_ * N_ + b * N_ + i] = m_run;
        rowsumS[seg * B_ * N_ + b * N_ + i] = s_run;
    }
}

// ---------- combine segments + per-batch reduce: rowscale_i = exp(rmax_i-gmax)/total ----------
__global__ void k_gred(const float* __restrict__ rowmaxS, const float* __restrict__ rowsumS,
                       float* __restrict__ rowmaxC, float* __restrict__ rowscale) {
    int b = blockIdx.x, tid = threadIdx.x;   // 512
    __shared__ float mred[512], sred[512];
    float m = -1e30f, s = 0.f;
    if (tid < N_) {
#pragma unroll
        for (int g = 0; g < SEG_; ++g) {
            float mg = rowmaxS[g * B_ * N_ + b * N_ + tid];
            float sg = rowsumS[g * B_ * N_ + b * N_ + tid];
            float mn = fmaxf(m, mg);
            s = s * expf(m - mn) + sg * expf(mg - mn);
            m = mn;
        }
    }
    mred[tid] = m;
    __syncthreads();
    for (int st = 256; st > 0; st >>= 1) {
        if (tid < st) mred[tid] = fmaxf(mred[tid], mred[tid + st]);
        __syncthreads();
    }
    float gm = mred[0];
    sred[tid] = (tid < N_) ? s * expf(m - gm) : 0.f;
    __syncthreads();
    for (int st = 256; st > 0; st >>= 1) {
        if (tid < st) sred[tid] += sred[tid + st];
        __syncthreads();
    }
    float inv = 1.f / sred[0];
    if (tid < N_) {
        rowmaxC[b * N_ + tid] = m;
        rowscale[b * N_ + tid] = expf(m - gm) * inv;
    }
}

// -------------------- phase 2: x (algebraic LN) + fused att normalize/write ----------
__global__ __launch_bounds__(256) void k_x(
    const float* __restrict__ inp, const float* __restrict__ pos,
    const float* __restrict__ coeffF, const float* __restrict__ scal,
    const float* __restrict__ vbeta, const float* __restrict__ vW2,
    const float* __restrict__ vb2, float* __restrict__ scoresAtt,
    const float* __restrict__ rowmax, const float* __restrict__ rowscale,
    float* __restrict__ xout) {
    int i = blockIdx.x, b = blockIdx.y;
    int tid = threadIdx.x;
    int jsub = tid >> 3, dg = tid & 7;

    __shared__ float accH[32 * 128];
    __shared__ float accI[32 * 64];
    __shared__ float accS[32];

    float cA[16], cB[16], cC[16], vB[16];
#pragma unroll
    for (int dd = 0; dd < 16; ++dd) {
        int d = dg * 16 + dd;
        cA[dd] = coeffF[d]; cB[dd] = coeffF[128 + d];
        cC[dd] = coeffF[256 + d]; vB[dd] = vbeta[d];
    }
    const float Saa = scal[0], Sbb = scal[1], Scc = scal[2];
    const float Sab = scal[3], Sac = scal[4], Sbc = scal[5];
    const float rmaxI = rowmax[b * N_ + i];
    const float rscaleI = rowscale[b * N_ + i];

    float aH[16];
    float aI[8];
#pragma unroll
    for (int dd = 0; dd < 16; ++dd) aH[dd] = 0.f;
#pragma unroll
    for (int ff = 0; ff < 8; ++ff) aI[ff] = 0.f;
    float aS = 0.f;

    const float* pi = pos + (size_t)(b * N_ + i) * 3;
    float ax = pi[0], ay = pi[1], az = pi[2];

    for (int jc = 0; jc < 12; ++jc) {
        int j = jc * 32 + jsub;
        const float* pj = pos + (size_t)(b * N_ + j) * 3;
        float bx = pj[0], by = pj[1], bz = pj[2];
        float dotv = ax * bx + ay * by + az * bz;
        float cx = ay * bz - az * by;
        float cy = az * bx - ax * bz;
        float cz = ax * by - ay * bx;
        float cns = cx * cx + cy * cy + cz * cz;
        float cn = sqrtf(cns);

        size_t sidx = (size_t)(b * N_ + i) * N_ + j;
        float sc = scoresAtt[sidx];
        float a = expf(sc - rmaxI) * rscaleI;
        if (dg == 0) scoresAtt[sidx] = a;   // same-wave: all 8 readers read before this write

        float var = Saa * dotv * dotv + Sbb * cns + Scc +
                    2.f * (Sab * dotv * cn + Sac * dotv + Sbc * cn);
        float rstd = rsqrtf(var + LN_EPS);
        float dr = dotv * rstd, cr = cn * rstd;
#pragma unroll
        for (int dd = 0; dd < 16; ++dd) {
            float v = fmaf(dr, cA[dd], fmaf(cr, cB[dd], fmaf(rstd, cC[dd], vB[dd])));
            aH[dd] = fmaf(a, fmaxf(v, 0.f), aH[dd]);
        }
#pragma unroll
        for (int ff = 0; ff < 8; ++ff) {
            int f = dg * 8 + ff;
            aI[ff] = fmaf(a, inp[(size_t)(b * N_ + j) * F_ + f], aI[ff]);
        }
        if (dg == 0) aS += a;
    }

#pragma unroll
    for (int dd = 0; dd < 16; ++dd) accH[jsub * 128 + dg * 16 + dd] = aH[dd];
#pragma unroll
    for (int ff = 0; ff < 8; ++ff) accI[jsub * 64 + dg * 8 + ff] = aI[ff];
    if (dg == 0) accS[jsub] = aS;
    __syncthreads();

    for (int st = 16; st > 0; st >>= 1) {
        if (jsub < st) {
#pragma unroll
            for (int dd = 0; dd < 16; ++dd)
                accH[jsub * 128 + dg * 16 + dd] += accH[(jsub + st) * 128 + dg * 16 + dd];
#pragma unroll
            for (int ff = 0; ff < 8; ++ff)
                accI[jsub * 64 + dg * 8 + ff] += accI[(jsub + st) * 64 + dg * 8 + ff];
            if (dg == 0) accS[jsub] += accS[jsub + st];
        }
        __syncthreads();
    }

    if (tid < F_) {
        int f = tid;
        float s = accS[0];
        float xv = 0.f;
#pragma unroll
        for (int d = 0; d < H_; ++d) xv = fmaf(accH[d], vW2[d * F_ + f], xv);
        float r = 0.5f * (xv + s * vb2[f]) +
                  0.25f * (s * inp[(size_t)(b * N_ + i) * F_ + f] + accI[f]);
        xout[(size_t)(b * N_ + i) * F_ + f] = r;
    }
}

// -------------------- launch --------------------

extern "C" void kernel_launch(void* const* d_in, const int* in_sizes, int n_in,
                              void* d_out, int out_size, void* d_ws, size_t ws_size,
                              hipStream_t stream) {
    const float* inp   = (const float*)d_in[0];
    const float* pos   = (const float*)d_in[1];
    const float* vW1   = (const float*)d_in[2];
    const float* vb1   = (const float*)d_in[3];
    const float* vg    = (const float*)d_in[4];
    const float* vbeta = (const float*)d_in[5];
    const float* vW2   = (const float*)d_in[6];
    const float* vb2   = (const float*)d_in[7];
    const float* sW1   = (const float*)d_in[8];
    const float* sb1   = (const float*)d_in[9];
    const float* sW2   = (const float*)d_in[10];
    const float* sb2   = (const float*)d_in[11];

    float* xout   = (float*)d_out;                 // B*N*F
    float* attout = xout + B_ * N_ * F_;           // B*N*N (scores -> att in place)

    unsigned short* W2hT   = (unsigned short*)d_ws;                  // 32KB fp16
    unsigned int*   coeffP = (unsigned int*)((char*)d_ws + 32768);   // 1KB packed f16x2
    float*          scal   = (float*)((char*)d_ws + 33792);          // 6 scalars
    float*          coeffF = (float*)((char*)d_ws + 34816);          // 3x128 fp32
    float* t        = (float*)((char*)d_ws + 36864);                 // B*N*128 fp32
    float* rowmaxS  = t + B_ * N_ * H_;                              // SEG*B*N
    float* rowsumS  = rowmaxS + SEG_ * B_ * N_;                      // SEG*B*N
    float* rowmaxC  = rowsumS + SEG_ * B_ * N_;                      // B*N
    float* rowscale = rowmaxC + B_ * N_;                             // B*N

    k_prep_w2p<<<64, 256, 0, stream>>>(vW2, sW1, W2hT);
    k_prep_coeff<<<1, 128, 0, stream>>>(vW1, vb1, vg, vbeta, coeffP, scal, coeffF);
    k_prep_t<<<B_ * N_, 128, 0, stream>>>(inp, sW1, vb2, sb1, t);
    k_scores<<<dim3(96 * SEG_, B_), 256, 0, stream>>>(
        pos, coeffP, scal, W2hT, t, sW2, sb2, attout, rowmaxS, rowsumS);
    k_gred<<<B_, 512, 0, stream>>>(rowmaxS, rowsumS, rowmaxC, rowscale);
    k_x<<<dim3(N_, B_), 256, 0, stream>>>(inp, pos, coeffF, scal, vbeta, vW2, vb2,
                                          attout, rowmaxC, rowscale, xout);
}

// Round 12
// 193.394 us; speedup vs baseline: 1.2794x; 1.2794x over previous
//
#include <hip/hip_runtime.h>
#include <hip/hip_bf16.h>
#include <math.h>

#define B_ 8
#define N_ 384
#define F_ 64
#define H_ 128
#define LN_EPS 1e-5f

typedef _Float16 f16;
typedef f16 f16x2 __attribute__((ext_vector_type(2)));
typedef f16 f16x4 __attribute__((ext_vector_type(4)));
typedef f16 f16x8 __attribute__((ext_vector_type(8)));
typedef float f32x4v __attribute__((ext_vector_type(4)));

static __device__ __forceinline__ f16x2 u2h(unsigned int u) {
    union { unsigned int u; f16x2 h; } c; c.u = u; return c.h;
}

// -------------------- fused setup kernel --------------------
// blockIdx.x < B_*N_          : t-row precompute (128 thr)
// blockIdx.x < B_*N_ + 128    : W2hT chunk (128 thr x 128 blocks = 16384)
// blockIdx.x == B_*N_ + 128   : algebraic-LN coefficients
__global__ __launch_bounds__(128) void k_prep(
    const float* __restrict__ inp, const float* __restrict__ sW1,
    const float* __restrict__ vb2, const float* __restrict__ sb1,
    const float* __restrict__ vW2, const float* __restrict__ vW1,
    const float* __restrict__ vb1, const float* __restrict__ vg,
    const float* __restrict__ vbeta,
    float* __restrict__ t, unsigned short* __restrict__ W2hT,
    unsigned int* __restrict__ coeffP, float* __restrict__ scal,
    float* __restrict__ coeffF) {
    __shared__ float red[128];
    __shared__ float caS[128], cbS[128], ccS[128];
    const int bx = blockIdx.x;
    const int tid = threadIdx.x;

    if (bx < B_ * N_) {
        // t[row][n] = sum_f (0.25*(in[row,f]+vb2[f])) * sW1[f,n] + 0.5*sb1[n]
        int row = bx, n = tid;
        float acc = 0.f;
#pragma unroll
        for (int f = 0; f < F_; ++f)
            acc = fmaf(0.25f * (inp[row * F_ + f] + vb2[f]), sW1[f * H_ + n], acc);
        t[row * H_ + n] = acc + 0.5f * sb1[n];
        return;
    }
    if (bx < B_ * N_ + 128) {
        // W2hT[n][k] = fp16(0.5 * sum_f vW2[k,f]*sW1[f,n]), transposed
        int idx = (bx - B_ * N_) * 128 + tid;
        int k = idx >> 7, n = idx & 127;
        float acc = 0.f;
#pragma unroll
        for (int f = 0; f < F_; ++f) acc = fmaf(vW2[k * F_ + f], sW1[f * H_ + n], acc);
        f16 hv = (f16)(0.5f * acc);
        W2hT[n * H_ + k] = *reinterpret_cast<unsigned short*>(&hv);
        return;
    }

    // ---- algebraic-LN coefficients ----
    const int d = tid;   // 128
    float a = vW1[d], bb = vW1[H_ + d], c = vb1[d];
    float mA, mB, mC, Saa, Sbb, Scc, Sab, Sac, Sbc;
    float ca, cb, cc;
#define BMEAN(OUT, VAL)                                                  \
    red[d] = (VAL); __syncthreads();                                     \
    for (int st = 64; st > 0; st >>= 1) {                                \
        if (d < st) red[d] += red[d + st];                               \
        __syncthreads();                                                 \
    }                                                                    \
    OUT = red[0] * (1.f / 128.f); __syncthreads();

    BMEAN(mA, a); BMEAN(mB, bb); BMEAN(mC, c);
    ca = a - mA; cb = bb - mB; cc = c - mC;
    caS[d] = ca * vg[d]; cbS[d] = cb * vg[d]; ccS[d] = cc * vg[d];
    BMEAN(Saa, ca * ca); BMEAN(Sbb, cb * cb); BMEAN(Scc, cc * cc);
    BMEAN(Sab, ca * cb); BMEAN(Sac, ca * cc); BMEAN(Sbc, cb * cc);
#undef BMEAN
    __syncthreads();
    coeffF[d] = caS[d]; coeffF[128 + d] = cbS[d]; coeffF[256 + d] = ccS[d];
    if (d < 64) {
        int d0 = 2 * d;
        union { f16x2 h; unsigned int u; } cv;
        cv.h = (f16x2){(f16)caS[d0], (f16)caS[d0 + 1]};   coeffP[d]       = cv.u;
        cv.h = (f16x2){(f16)cbS[d0], (f16)cbS[d0 + 1]};   coeffP[64 + d]  = cv.u;
        cv.h = (f16x2){(f16)ccS[d0], (f16)ccS[d0 + 1]};   coeffP[128 + d] = cv.u;
        cv.h = (f16x2){(f16)vbeta[d0], (f16)vbeta[d0 + 1]}; coeffP[192 + d] = cv.u;
    }
    if (d == 0) {
        scal[0] = Saa; scal[1] = Sbb; scal[2] = Scc;
        scal[3] = Sab; scal[4] = Sac; scal[5] = Sbc;
    }
}

// -------------------- phase 1: scores (R10-proven config: SEG reverted) --------------------
// Block = 4 waves; wave w owns i-row blockIdx.x*4+w; 24 j-tiles of 16 pairs, barrier-free.
// Cross-tile software pipeline (double-buffered rht). A-frags of W' resident in 128 VGPR.
// Epilogue: online (rowmax, rowsum) per row.
// __launch_bounds__(256) only — min-waves arg caps VGPR at 256/arg => spills (R5/R6).
// R11 lesson: SEG-splitting the j-range tripled the prologue without raising occupancy — reverted.
__global__ __launch_bounds__(256) void k_scores(
    const float* __restrict__ pos, const unsigned int* __restrict__ coeffP,
    const float* __restrict__ scal, const unsigned short* __restrict__ W2hT,
    const float* __restrict__ t, const float* __restrict__ sW2,
    const float* __restrict__ sb2, float* __restrict__ scores,
    float* __restrict__ rowmax, float* __restrict__ rowsum) {
    __shared__ __align__(16) char smem[36864];

    const int tid = threadIdx.x;
    const int b = blockIdx.y;
    const int w = tid >> 6, lane = tid & 63;
    const int i = blockIdx.x * 4 + w;
    const int ln = lane & 15, h4 = lane >> 4;

    char* rht0 = smem + w * 8192;
    char* rht1 = rht0 + 4096;
    char* tiS = smem + 32768 + w * 512;
    char* swS = smem + 34816 + w * 512;

    if (lane < 32) {
        *(float4*)(tiS + lane * 16) = *(const float4*)(t + (size_t)(b * N_ + i) * H_ + lane * 4);
        *(float4*)(swS + lane * 16) = *(const float4*)(sW2 + lane * 4);
    }

    f16x8 aF[8][4];
#pragma unroll
    for (int mf = 0; mf < 8; ++mf)
#pragma unroll
        for (int kc = 0; kc < 4; ++kc)
            aF[mf][kc] = *(const f16x8*)(W2hT + (mf * 16 + ln) * H_ + kc * 32 + h4 * 8);

    const int lA = lane & 7;
    const uint4 cagA = *(const uint4*)(coeffP + lA * 8);
    const uint4 cagB = *(const uint4*)(coeffP + lA * 8 + 4);
    const uint4 cbgA = *(const uint4*)(coeffP + 64 + lA * 8);
    const uint4 cbgB = *(const uint4*)(coeffP + 64 + lA * 8 + 4);
    const uint4 ccgA = *(const uint4*)(coeffP + 128 + lA * 8);
    const uint4 ccgB = *(const uint4*)(coeffP + 128 + lA * 8 + 4);
    const uint4 vbA  = *(const uint4*)(coeffP + 192 + lA * 8);
    const uint4 vbB  = *(const uint4*)(coeffP + 192 + lA * 8 + 4);

    const float Saa = scal[0], Sbb = scal[1], Scc = scal[2];
    const float Sab = scal[3], Sac = scal[4], Sbc = scal[5];
    const float sb2v = sb2[0];

    const float* pi = pos + (size_t)(b * N_ + i) * 3;
    const float ax = pi[0], ay = pi[1], az = pi[2];
    const int pA8 = lane >> 3;

    float* scoreRow = scores + (size_t)(b * N_ + i) * N_;

    float m_run = -1e30f, s_run = 0.f;

    auto prefPos = [&](int jt, float& b0x, float& b0y, float& b0z,
                       float& b1x, float& b1y, float& b1z) {
        const float* pj0 = pos + (size_t)(b * N_ + jt * 16 + pA8) * 3;
        const float* pj1 = pj0 + 24;
        b0x = pj0[0]; b0y = pj0[1]; b0z = pj0[2];
        b1x = pj1[0]; b1y = pj1[1]; b1z = pj1[2];
    };

    auto accInit = [&](f32x4v (&acc)[8], int jt) {
        const float* tjB = t + (size_t)(b * N_ + jt * 16 + ln) * H_ + h4 * 4;
#pragma unroll
        for (int mf = 0; mf < 8; ++mf) {
            float4 tiv = *(const float4*)(tiS + mf * 64 + h4 * 16);
            float4 tj = *(const float4*)(tjB + mf * 16);
            acc[mf][0] = tiv.x + tj.x;
            acc[mf][1] = tiv.y + tj.y;
            acc[mf][2] = tiv.z + tj.z;
            acc[mf][3] = tiv.w + tj.w;
        }
    };

    auto phaseApass = [&](char* buf, int q, float bx, float by, float bz) {
        const int pq = q * 8 + pA8;
        float dotv = ax * bx + ay * by + az * bz;
        float cx = ay * bz - az * by;
        float cy = az * bx - ax * bz;
        float cz = ax * by - ay * bx;
        float cns = cx * cx + cy * cy + cz * cz;
        float cn = sqrtf(cns);
        float var = Saa * dotv * dotv + Sbb * cns + Scc +
                    2.f * (Sab * dotv * cn + Sac * dotv + Sbc * cn);
        float rstd = rsqrtf(var + LN_EPS);
        f16 d2 = (f16)(dotv * rstd), c2 = (f16)(cn * rstd), r2 = (f16)rstd;
        f16x2 D2 = {d2, d2}, C2 = {c2, c2}, R2 = {r2, r2};
        const f16x2 Z = {(f16)0.f, (f16)0.f};

        f16x2 vp0 = __builtin_elementwise_max(D2 * u2h(cagA.x) + (C2 * u2h(cbgA.x) + (R2 * u2h(ccgA.x) + u2h(vbA.x))), Z);
        f16x2 vp1 = __builtin_elementwise_max(D2 * u2h(cagA.y) + (C2 * u2h(cbgA.y) + (R2 * u2h(ccgA.y) + u2h(vbA.y))), Z);
        f16x2 vp2 = __builtin_elementwise_max(D2 * u2h(cagA.z) + (C2 * u2h(cbgA.z) + (R2 * u2h(ccgA.z) + u2h(vbA.z))), Z);
        f16x2 vp3 = __builtin_elementwise_max(D2 * u2h(cagA.w) + (C2 * u2h(cbgA.w) + (R2 * u2h(ccgA.w) + u2h(vbA.w))), Z);
        f16x2 vp4 = __builtin_elementwise_max(D2 * u2h(cagB.x) + (C2 * u2h(cbgB.x) + (R2 * u2h(ccgB.x) + u2h(vbB.x))), Z);
        f16x2 vp5 = __builtin_elementwise_max(D2 * u2h(cagB.y) + (C2 * u2h(cbgB.y) + (R2 * u2h(ccgB.y) + u2h(vbB.y))), Z);
        f16x2 vp6 = __builtin_elementwise_max(D2 * u2h(cagB.z) + (C2 * u2h(cbgB.z) + (R2 * u2h(ccgB.z) + u2h(vbB.z))), Z);
        f16x2 vp7 = __builtin_elementwise_max(D2 * u2h(cagB.w) + (C2 * u2h(cbgB.w) + (R2 * u2h(ccgB.w) + u2h(vbB.w))), Z);

        f16x4 q0 = __builtin_shufflevector(vp0, vp1, 0, 1, 2, 3);
        f16x4 q1 = __builtin_shufflevector(vp2, vp3, 0, 1, 2, 3);
        f16x4 q2 = __builtin_shufflevector(vp4, vp5, 0, 1, 2, 3);
        f16x4 q3 = __builtin_shufflevector(vp6, vp7, 0, 1, 2, 3);
        f16x8 o0 = __builtin_shufflevector(q0, q1, 0, 1, 2, 3, 4, 5, 6, 7);
        f16x8 o1 = __builtin_shufflevector(q2, q3, 0, 1, 2, 3, 4, 5, 6, 7);

        const int rb = pq * 256, sw = (pq & 7) << 4;
        *(f16x8*)(buf + rb + ((lA * 32) ^ sw)) = o0;
        *(f16x8*)(buf + rb + ((lA * 32 + 16) ^ sw)) = o1;
    };

    auto gemm = [&](f32x4v (&acc)[8], char* buf) {
#pragma unroll
        for (int kc = 0; kc < 4; ++kc) {
            f16x8 bF = *(const f16x8*)(buf + ln * 256 + ((kc * 64 + h4 * 16) ^ ((ln & 7) << 4)));
#pragma unroll
            for (int mf = 0; mf < 8; ++mf)
                acc[mf] = __builtin_amdgcn_mfma_f32_16x16x32_f16(aF[mf][kc], bF, acc[mf], 0, 0, 0);
        }
    };

    auto phaseC = [&](f32x4v (&acc)[8], int jt) {
        float part = 0.f;
#pragma unroll
        for (int mf = 0; mf < 8; ++mf) {
            float4 swv = *(const float4*)(swS + mf * 64 + h4 * 16);
            part += fmaxf(acc[mf][0], 0.f) * swv.x;
            part += fmaxf(acc[mf][1], 0.f) * swv.y;
            part += fmaxf(acc[mf][2], 0.f) * swv.z;
            part += fmaxf(acc[mf][3], 0.f) * swv.w;
        }
        part += __shfl_xor(part, 16);
        part += __shfl_xor(part, 32);
        float sc = part + sb2v;
        if (h4 == 0) scoreRow[jt * 16 + ln] = sc;
        float mn = fmaxf(m_run, sc);
        s_run = s_run * expf(m_run - mn) + expf(sc - mn);
        m_run = mn;
    };

    f32x4v accP[8], accQ[8];
    float A0x, A0y, A0z, A1x, A1y, A1z;
    float B0x, B0y, B0z, B1x, B1y, B1z;

    prefPos(0, A0x, A0y, A0z, A1x, A1y, A1z);
    accInit(accP, 0);
    phaseApass(rht0, 0, A0x, A0y, A0z);
    phaseApass(rht0, 1, A1x, A1y, A1z);

#pragma unroll 1
    for (int jt = 0; jt < 24; jt += 2) {
        const int j1 = jt + 1;
        const int j2 = (jt + 2 < 24) ? (jt + 2) : 23;
        prefPos(j1, B0x, B0y, B0z, B1x, B1y, B1z);
        accInit(accQ, j1);
        gemm(accP, rht0);
        phaseApass(rht1, 0, B0x, B0y, B0z);
        phaseApass(rht1, 1, B1x, B1y, B1z);
        phaseC(accP, jt);
        prefPos(j2, A0x, A0y, A0z, A1x, A1y, A1z);
        accInit(accP, j2);
        gemm(accQ, rht1);
        phaseApass(rht0, 0, A0x, A0y, A0z);
        phaseApass(rht0, 1, A1x, A1y, A1z);
        phaseC(accQ, j1);
    }

#pragma unroll
    for (int d = 1; d < 16; d <<= 1) {
        float mo = __shfl_xor(m_run, d);
        float so = __shfl_xor(s_run, d);
        float mn = fmaxf(m_run, mo);
        s_run = s_run * expf(m_run - mn) + so * expf(mo - mn);
        m_run = mn;
    }
    if (lane == 0) {
        rowmax[b * N_ + i] = m_run;
        rowsum[b * N_ + i] = s_run;
    }
}

// -------------------- per-batch softmax reduce: rowscale_i = exp(rmax_i-gmax)/total ----------
__global__ void k_gred(const float* __restrict__ rowmax, const float* __restrict__ rowsum,
                       float* __restrict__ rowscale) {
    int b = blockIdx.x, tid = threadIdx.x;   // 512
    __shared__ float mred[512], sred[512];
    float m = (tid < N_) ? rowmax[b * N_ + tid] : -1e30f;
    float s = (tid < N_) ? rowsum[b * N_ + tid] : 0.f;
    mred[tid] = m;
    __syncthreads();
    for (int st = 256; st > 0; st >>= 1) {
        if (tid < st) mred[tid] = fmaxf(mred[tid], mred[tid + st]);
        __syncthreads();
    }
    float gm = mred[0];
    sred[tid] = s * expf(m - gm);
    __syncthreads();
    for (int st = 256; st > 0; st >>= 1) {
        if (tid < st) sred[tid] += sred[tid + st];
        __syncthreads();
    }
    float inv = 1.f / sred[0];
    if (tid < N_) rowscale[b * N_ + tid] = expf(m - gm) * inv;
}

// -------------------- phase 2: x (algebraic LN, shuffle-reduce, coalesced att write) ----------
// One block per (b,i). Loop reads raw scores (no in-loop store); 3-step shfl_xor reduce
// (masks 8/16/32 = jsub bits) -> 4 wave partials in LDS -> combine; separate coalesced
// att normalize pass. 2 barriers total (was 6).
__global__ __launch_bounds__(256) void k_x(
    const float* __restrict__ inp, const float* __restrict__ pos,
    const float* __restrict__ coeffF, const float* __restrict__ scal,
    const float* __restrict__ vbeta, const float* __restrict__ vW2,
    const float* __restrict__ vb2, float* __restrict__ scoresAtt,
    const float* __restrict__ rowmax, const float* __restrict__ rowscale,
    float* __restrict__ xout) {
    int i = blockIdx.x, b = blockIdx.y;
    int tid = threadIdx.x;
    int lane = tid & 63, w = tid >> 6;
    int jsub = tid >> 3, dg = tid & 7;

    __shared__ float accHp[4 * 128];
    __shared__ float accIp[4 * 64];
    __shared__ float accSp[4];

    float cA[16], cB[16], cC[16], vB[16];
#pragma unroll
    for (int dd = 0; dd < 16; ++dd) {
        int d = dg * 16 + dd;
        cA[dd] = coeffF[d]; cB[dd] = coeffF[128 + d];
        cC[dd] = coeffF[256 + d]; vB[dd] = vbeta[d];
    }
    const float Saa = scal[0], Sbb = scal[1], Scc = scal[2];
    const float Sab = scal[3], Sac = scal[4], Sbc = scal[5];
    const float rmaxI = rowmax[b * N_ + i];
    const float rscaleI = rowscale[b * N_ + i];

    float aH[16];
    float aI[8];
#pragma unroll
    for (int dd = 0; dd < 16; ++dd) aH[dd] = 0.f;
#pragma unroll
    for (int ff = 0; ff < 8; ++ff) aI[ff] = 0.f;
    float aS = 0.f;

    const float* pi = pos + (size_t)(b * N_ + i) * 3;
    float ax = pi[0], ay = pi[1], az = pi[2];
    float* scoreRow = scoresAtt + (size_t)(b * N_ + i) * N_;

    for (int jc = 0; jc < 12; ++jc) {
        int j = jc * 32 + jsub;
        const float* pj = pos + (size_t)(b * N_ + j) * 3;
        float bx = pj[0], by = pj[1], bz = pj[2];
        float dotv = ax * bx + ay * by + az * bz;
        float cx = ay * bz - az * by;
        float cy = az * bx - ax * bz;
        float cz = ax * by - ay * bx;
        float cns = cx * cx + cy * cy + cz * cz;
        float cn = sqrtf(cns);

        float sc = scoreRow[j];
        float a = expf(sc - rmaxI) * rscaleI;

        float var = Saa * dotv * dotv + Sbb * cns + Scc +
                    2.f * (Sab * dotv * cn + Sac * dotv + Sbc * cn);
        float rstd = rsqrtf(var + LN_EPS);
        float dr = dotv * rstd, cr = cn * rstd;
#pragma unroll
        for (int dd = 0; dd < 16; ++dd) {
            float v = fmaf(dr, cA[dd], fmaf(cr, cB[dd], fmaf(rstd, cC[dd], vB[dd])));
            aH[dd] = fmaf(a, fmaxf(v, 0.f), aH[dd]);
        }
#pragma unroll
        for (int ff = 0; ff < 8; ++ff) {
            int f = dg * 8 + ff;
            aI[ff] = fmaf(a, inp[(size_t)(b * N_ + j) * F_ + f], aI[ff]);
        }
        if (dg == 0) aS += a;
    }

    // wave-level reduce over jsub (lane bits 3/4/5), dg preserved
#pragma unroll
    for (int m = 8; m <= 32; m <<= 1) {
#pragma unroll
        for (int dd = 0; dd < 16; ++dd) aH[dd] += __shfl_xor(aH[dd], m);
#pragma unroll
        for (int ff = 0; ff < 8; ++ff) aI[ff] += __shfl_xor(aI[ff], m);
        aS += __shfl_xor(aS, m);
    }
    if (lane < 8) {
#pragma unroll
        for (int dd = 0; dd < 16; ++dd) accHp[w * 128 + lane * 16 + dd] = aH[dd];
#pragma unroll
        for (int ff = 0; ff < 8; ++ff) accIp[w * 64 + lane * 8 + ff] = aI[ff];
        if (lane == 0) accSp[w] = aS;
    }
    __syncthreads();

    // coalesced att normalize pass (loop reads are complete past the barrier)
    {
        float sc = scoreRow[tid];
        scoreRow[tid] = expf(sc - rmaxI) * rscaleI;
        if (tid < N_ - 256) {
            float sc2 = scoreRow[tid + 256];
            scoreRow[tid + 256] = expf(sc2 - rmaxI) * rscaleI;
        }
    }

    // combine 4 wave partials
    if (tid < 128) {
        accHp[tid] = accHp[tid] + accHp[128 + tid] + accHp[256 + tid] + accHp[384 + tid];
    } else if (tid < 192) {
        int f = tid - 128;
        accIp[f] = accIp[f] + accIp[64 + f] + accIp[128 + f] + accIp[192 + f];
    } else if (tid == 192) {
        accSp[0] = accSp[0] + accSp[1] + accSp[2] + accSp[3];
    }
    __syncthreads();

    if (tid < F_) {
        int f = tid;
        float s = accSp[0];
        float xv = 0.f;
#pragma unroll
        for (int d = 0; d < H_; ++d) xv = fmaf(accHp[d], vW2[d * F_ + f], xv);
        float r = 0.5f * (xv + s * vb2[f]) +
                  0.25f * (s * inp[(size_t)(b * N_ + i) * F_ + f] + accIp[f]);
        xout[(size_t)(b * N_ + i) * F_ + f] = r;
    }
}

// -------------------- launch --------------------

extern "C" void kernel_launch(void* const* d_in, const int* in_sizes, int n_in,
                              void* d_out, int out_size, void* d_ws, size_t ws_size,
                              hipStream_t stream) {
    const float* inp   = (const float*)d_in[0];
    const float* pos   = (const float*)d_in[1];
    const float* vW1   = (const float*)d_in[2];
    const float* vb1   = (const float*)d_in[3];
    const float* vg    = (const float*)d_in[4];
    const float* vbeta = (const float*)d_in[5];
    const float* vW2   = (const float*)d_in[6];
    const float* vb2   = (const float*)d_in[7];
    const float* sW1   = (const float*)d_in[8];
    const float* sb1   = (const float*)d_in[9];
    const float* sW2   = (const float*)d_in[10];
    const float* sb2   = (const float*)d_in[11];

    float* xout   = (float*)d_out;                 // B*N*F
    float* attout = xout + B_ * N_ * F_;           // B*N*N (scores -> att in place)

    unsigned short* W2hT   = (unsigned short*)d_ws;                  // 32KB fp16
    unsigned int*   coeffP = (unsigned int*)((char*)d_ws + 32768);   // 1KB packed f16x2
    float*          scal   = (float*)((char*)d_ws + 33792);          // 6 scalars
    float*          coeffF = (float*)((char*)d_ws + 34816);          // 3x128 fp32
    float* t        = (float*)((char*)d_ws + 36864);                 // B*N*128 fp32
    float* rowmax   = t + B_ * N_ * H_;                              // B*N
    float* rowsum   = rowmax + B_ * N_;                              // B*N
    float* rowscale = rowsum + B_ * N_;                              // B*N

    k_prep<<<B_ * N_ + 128 + 1, 128, 0, stream>>>(
        inp, sW1, vb2, sb1, vW2, vW1, vb1, vg, vbeta,
        t, W2hT, coeffP, scal, coeffF);
    k_scores<<<dim3(96, B_), 256, 0, stream>>>(
        pos, coeffP, scal, W2hT, t, sW2, sb2, attout, rowmax, rowsum);
    k_gred<<<B_, 512, 0, stream>>>(rowmax, rowsum, rowscale);
    k_x<<<dim3(N_, B_), 256, 0, stream>>>(inp, pos, coeffF, scal, vbeta, vW2, vb2,
                                          attout, rowmax, rowscale, xout);
}

// Round 13
// 167.881 us; speedup vs baseline: 1.4738x; 1.1520x over previous
//
#include <hip/hip_runtime.h>
#include <hip/hip_bf16.h>
#include <math.h>

#define B_ 8
#define N_ 384
#define F_ 64
#define H_ 128
#define LN_EPS 1e-5f

typedef _Float16 f16;
typedef f16 f16x2 __attribute__((ext_vector_type(2)));
typedef f16 f16x4 __attribute__((ext_vector_type(4)));
typedef f16 f16x8 __attribute__((ext_vector_type(8)));
typedef float f32x4v __attribute__((ext_vector_type(4)));

static __device__ __forceinline__ f16x2 u2h(unsigned int u) {
    union { unsigned int u; f16x2 h; } c; c.u = u; return c.h;
}
static __device__ __forceinline__ unsigned int h2u(f16 a, f16 b) {
    union { f16x2 h; unsigned int u; } c; c.h = (f16x2){a, b}; return c.u;
}

// packed-permuted index helpers: uint slot u = h4*16 + mf*2 + p packs
// elements (n, n+1) with n = mf*16 + h4*4 + 2p  (matches MFMA C/D row layout)
static __device__ __forceinline__ void perm_idx(int m, int& u, int& n0) {
    int h4 = (m >> 1) & 3, mf = m >> 3, p = m & 1;
    u = h4 * 16 + mf * 2 + p;
    n0 = mf * 16 + h4 * 4 + 2 * p;
}

// -------------------- fused setup kernel --------------------
// blockIdx.x < B_*N_        : t16 row (packed-permuted fp16 of the affine row vec)
// blockIdx.x < B_*N_ + 128  : W2hT chunk
// blockIdx.x == B_*N_ + 128 : algebraic-LN coefficients + sw16 pack
__global__ __launch_bounds__(128) void k_prep(
    const float* __restrict__ inp, const float* __restrict__ sW1,
    const float* __restrict__ vb2, const float* __restrict__ sb1,
    const float* __restrict__ vW2, const float* __restrict__ vW1,
    const float* __restrict__ vb1, const float* __restrict__ vg,
    const float* __restrict__ vbeta, const float* __restrict__ sW2,
    unsigned int* __restrict__ t16, unsigned short* __restrict__ W2hT,
    unsigned int* __restrict__ coeffP, float* __restrict__ scal,
    float* __restrict__ coeffF, unsigned int* __restrict__ sw16) {
    __shared__ float red[128];
    __shared__ float caS[128], cbS[128], ccS[128];
    const int bx = blockIdx.x;
    const int tid = threadIdx.x;

    if (bx < B_ * N_) {
        // tt[n] = 0.25*(in[row]+vb2)@sW1[:,n] + 0.5*sb1[n] ; pack-permute to t16
        int row = bx, n = tid;
        float acc = 0.f;
#pragma unroll
        for (int f = 0; f < F_; ++f)
            acc = fmaf(0.25f * (inp[row * F_ + f] + vb2[f]), sW1[f * H_ + n], acc);
        red[n] = acc + 0.5f * sb1[n];
        __syncthreads();
        if (tid < 64) {
            int u, n0; perm_idx(tid, u, n0);
            t16[row * 64 + u] = h2u((f16)red[n0], (f16)red[n0 + 1]);
        }
        return;
    }
    if (bx < B_ * N_ + 128) {
        int idx = (bx - B_ * N_) * 128 + tid;
        int k = idx >> 7, n = idx & 127;
        float acc = 0.f;
#pragma unroll
        for (int f = 0; f < F_; ++f) acc = fmaf(vW2[k * F_ + f], sW1[f * H_ + n], acc);
        f16 hv = (f16)(0.5f * acc);
        W2hT[n * H_ + k] = *reinterpret_cast<unsigned short*>(&hv);
        return;
    }

    // ---- algebraic-LN coefficients + sw16 ----
    const int d = tid;   // 128
    float a = vW1[d], bb = vW1[H_ + d], c = vb1[d];
    float mA, mB, mC, Saa, Sbb, Scc, Sab, Sac, Sbc;
    float ca, cb, cc;
#define BMEAN(OUT, VAL)                                                  \
    red[d] = (VAL); __syncthreads();                                     \
    for (int st = 64; st > 0; st >>= 1) {                                \
        if (d < st) red[d] += red[d + st];                               \
        __syncthreads();                                                 \
    }                                                                    \
    OUT = red[0] * (1.f / 128.f); __syncthreads();

    BMEAN(mA, a); BMEAN(mB, bb); BMEAN(mC, c);
    ca = a - mA; cb = bb - mB; cc = c - mC;
    caS[d] = ca * vg[d]; cbS[d] = cb * vg[d]; ccS[d] = cc * vg[d];
    BMEAN(Saa, ca * ca); BMEAN(Sbb, cb * cb); BMEAN(Scc, cc * cc);
    BMEAN(Sab, ca * cb); BMEAN(Sac, ca * cc); BMEAN(Sbc, cb * cc);
#undef BMEAN
    __syncthreads();
    coeffF[d] = caS[d]; coeffF[128 + d] = cbS[d]; coeffF[256 + d] = ccS[d];
    if (d < 64) {
        int d0 = 2 * d;
        coeffP[d]       = h2u((f16)caS[d0], (f16)caS[d0 + 1]);
        coeffP[64 + d]  = h2u((f16)cbS[d0], (f16)cbS[d0 + 1]);
        coeffP[128 + d] = h2u((f16)ccS[d0], (f16)ccS[d0 + 1]);
        coeffP[192 + d] = h2u((f16)vbeta[d0], (f16)vbeta[d0 + 1]);
        int u, n0; perm_idx(d, u, n0);
        sw16[u] = h2u((f16)sW2[n0], (f16)sW2[n0 + 1]);
    }
    if (d == 0) {
        scal[0] = Saa; scal[1] = Sbb; scal[2] = Scc;
        scal[3] = Sab; scal[4] = Sac; scal[5] = Sbc;
    }
}

// -------------------- phase 1: scores (B-frag born in registers) --------------------
// Block = 4 waves; wave w owns i-row blockIdx.x*4+w; 24 j-tiles of 16 pairs, barrier-free
// after the one-time W'/sw16 LDS stage. Lane (ln,h4) computes pair ln's dims
// kc*32+h4*8..+7 directly as the MFMA B-fragment — rh NEVER touches LDS (no ds_write,
// no pack shuffles, no lgkm chain). A (W') read from LDS (32 dependency-free b128/tile).
// ti folds into acc-init from 16 resident packed regs; tj (packed fp16) issued at tile
// top, consumed at phaseC (~600cyc cover). Online (rowmax,rowsum) epilogue kept.
// __launch_bounds__(256) only — min-waves arg caps VGPR at 256/arg => spills (R5/R6).
__global__ __launch_bounds__(256) void k_scores(
    const float* __restrict__ pos, const unsigned int* __restrict__ coeffP,
    const float* __restrict__ scal, const unsigned short* __restrict__ W2hT,
    const unsigned int* __restrict__ t16, const unsigned int* __restrict__ sw16,
    const float* __restrict__ sb2, float* __restrict__ scores,
    float* __restrict__ rowmax, float* __restrict__ rowsum) {
    __shared__ __align__(16) char smem[33024];   // 32KB W' (swizzled) + 256B sw16

    const int tid = threadIdx.x;
    const int b = blockIdx.y;
    const int w = tid >> 6, lane = tid & 63;
    const int i = blockIdx.x * 4 + w;
    const int ln = lane & 15, h4 = lane >> 4;

    // ---- one-time stage: W' swizzled + sw16 ----
#pragma unroll
    for (int s = 0; s < 8; ++s) {
        int idx = tid + s * 256;
        int n = idx >> 4, c = idx & 15;
        uint4 v = *(const uint4*)(W2hT + n * H_ + c * 8);
        *(uint4*)(smem + ((n * 256 + c * 16) ^ ((n & 7) << 4))) = v;
    }
    if (tid < 64) ((unsigned int*)(smem + 32768))[tid] = sw16[tid];
    __syncthreads();

    // ---- resident state ----
    uint4 cagR[4], cbgR[4], ccgR[4], vbR[4];
#pragma unroll
    for (int kc = 0; kc < 4; ++kc) {
        cagR[kc] = *(const uint4*)(coeffP + kc * 16 + h4 * 4);
        cbgR[kc] = *(const uint4*)(coeffP + 64 + kc * 16 + h4 * 4);
        ccgR[kc] = *(const uint4*)(coeffP + 128 + kc * 16 + h4 * 4);
        vbR[kc]  = *(const uint4*)(coeffP + 192 + kc * 16 + h4 * 4);
    }
    unsigned int tih[16];
    {
        const unsigned int* tiP = t16 + (size_t)(b * N_ + i) * 64 + h4 * 16;
#pragma unroll
        for (int s = 0; s < 4; ++s) {
            uint4 v = *(const uint4*)(tiP + s * 4);
            tih[s * 4 + 0] = v.x; tih[s * 4 + 1] = v.y;
            tih[s * 4 + 2] = v.z; tih[s * 4 + 3] = v.w;
        }
    }
    const float Saa = scal[0], Sbb = scal[1], Scc = scal[2];
    const float Sab = scal[3], Sac = scal[4], Sbc = scal[5];
    const float sb2v = sb2[0];

    const float* pi = pos + (size_t)(b * N_ + i) * 3;
    const float ax = pi[0], ay = pi[1], az = pi[2];
    float* scoreRow = scores + (size_t)(b * N_ + i) * N_;
    const unsigned int* swp = (const unsigned int*)(smem + 32768) + h4 * 16;

    float m_run = -1e30f, s_run = 0.f;

    // pos prefetch for tile 0
    const float* pj0p = pos + (size_t)(b * N_ + ln) * 3;
    float bx = pj0p[0], by = pj0p[1], bz = pj0p[2];

#pragma unroll 1
    for (int jt = 0; jt < 24; ++jt) {
        const int j0 = jt * 16;

        // ---- tj prefetch (packed), consumed at phaseC ----
        const unsigned int* tjP = t16 + (size_t)(b * N_ + j0 + ln) * 64 + h4 * 16;
        uint4 tj0 = *(const uint4*)(tjP);
        uint4 tj1 = *(const uint4*)(tjP + 4);
        uint4 tj2 = *(const uint4*)(tjP + 8);
        uint4 tj3 = *(const uint4*)(tjP + 12);

        // ---- geometry (4 h4-replicas per pair) ----
        float dotv = ax * bx + ay * by + az * bz;
        float cx = ay * bz - az * by;
        float cy = az * bx - ax * bz;
        float cz = ax * by - ay * bx;
        float cns = cx * cx + cy * cy + cz * cz;
        float cn = sqrtf(cns);

        // pos prefetch for next tile (uniform-clamped address)
        {
            int jn = (jt < 23) ? (j0 + 16) : j0;
            const float* pn = pos + (size_t)(b * N_ + jn + ln) * 3;
            bx = pn[0]; by = pn[1]; bz = pn[2];
        }

        float var = Saa * dotv * dotv + Sbb * cns + Scc +
                    2.f * (Sab * dotv * cn + Sac * dotv + Sbc * cn);
        float rstd = rsqrtf(var + LN_EPS);
        f16 d2 = (f16)(dotv * rstd), c2 = (f16)(cn * rstd), r2 = (f16)rstd;
        f16x2 D2 = {d2, d2}, C2 = {c2, c2}, R2 = {r2, r2};
        const f16x2 Z = {(f16)0.f, (f16)0.f};

        // ---- B-fragments in registers ----
        f16x8 bF[4];
#pragma unroll
        for (int kc = 0; kc < 4; ++kc) {
            f16x2 vp0 = __builtin_elementwise_max(D2 * u2h(cagR[kc].x) + (C2 * u2h(cbgR[kc].x) + (R2 * u2h(ccgR[kc].x) + u2h(vbR[kc].x))), Z);
            f16x2 vp1 = __builtin_elementwise_max(D2 * u2h(cagR[kc].y) + (C2 * u2h(cbgR[kc].y) + (R2 * u2h(ccgR[kc].y) + u2h(vbR[kc].y))), Z);
            f16x2 vp2 = __builtin_elementwise_max(D2 * u2h(cagR[kc].z) + (C2 * u2h(cbgR[kc].z) + (R2 * u2h(ccgR[kc].z) + u2h(vbR[kc].z))), Z);
            f16x2 vp3 = __builtin_elementwise_max(D2 * u2h(cagR[kc].w) + (C2 * u2h(cbgR[kc].w) + (R2 * u2h(ccgR[kc].w) + u2h(vbR[kc].w))), Z);
            f16x4 q01 = __builtin_shufflevector(vp0, vp1, 0, 1, 2, 3);
            f16x4 q23 = __builtin_shufflevector(vp2, vp3, 0, 1, 2, 3);
            bF[kc] = __builtin_shufflevector(q01, q23, 0, 1, 2, 3, 4, 5, 6, 7);
        }

        // ---- acc init = ti (unpack resident tih) ----
        f32x4v acc[8];
#pragma unroll
        for (int mf = 0; mf < 8; ++mf) {
            f16x2 t0 = u2h(tih[mf * 2]);
            f16x2 t1 = u2h(tih[mf * 2 + 1]);
            acc[mf][0] = (float)t0[0]; acc[mf][1] = (float)t0[1];
            acc[mf][2] = (float)t1[0]; acc[mf][3] = (float)t1[1];
        }

        // ---- GEMM: A from LDS (dependency-free), B in regs ----
#pragma unroll
        for (int kc = 0; kc < 4; ++kc) {
            const int kb = (kc * 64 + h4 * 16) ^ ((ln & 7) << 4);
#pragma unroll
            for (int mf = 0; mf < 8; ++mf) {
                f16x8 aFr = *(const f16x8*)(smem + (mf * 16 + ln) * 256 + kb);
                acc[mf] = __builtin_amdgcn_mfma_f32_16x16x32_f16(aFr, bF[kc], acc[mf], 0, 0, 0);
            }
        }

        // ---- phaseC: +tj, relu, dot sw16, reduce over h4 ----
        unsigned int tju[16] = {tj0.x, tj0.y, tj0.z, tj0.w, tj1.x, tj1.y, tj1.z, tj1.w,
                                tj2.x, tj2.y, tj2.z, tj2.w, tj3.x, tj3.y, tj3.z, tj3.w};
        float part = 0.f;
#pragma unroll
        for (int mf = 0; mf < 8; ++mf) {
            uint2 swu = *(const uint2*)(swp + mf * 2);
            f16x2 s0 = u2h(swu.x), s1 = u2h(swu.y);
            f16x2 jh0 = u2h(tju[mf * 2]), jh1 = u2h(tju[mf * 2 + 1]);
            part += fmaxf(acc[mf][0] + (float)jh0[0], 0.f) * (float)s0[0];
            part += fmaxf(acc[mf][1] + (float)jh0[1], 0.f) * (float)s0[1];
            part += fmaxf(acc[mf][2] + (float)jh1[0], 0.f) * (float)s1[0];
            part += fmaxf(acc[mf][3] + (float)jh1[1], 0.f) * (float)s1[1];
        }
        part += __shfl_xor(part, 16);
        part += __shfl_xor(part, 32);
        float sc = part + sb2v;
        if (h4 == 0) scoreRow[j0 + ln] = sc;
        float mn = fmaxf(m_run, sc);
        s_run = s_run * expf(m_run - mn) + expf(sc - mn);
        m_run = mn;
    }

    // row-stat reduce across ln (h4 replicas identical), fixed shuffle tree
#pragma unroll
    for (int d = 1; d < 16; d <<= 1) {
        float mo = __shfl_xor(m_run, d);
        float so = __shfl_xor(s_run, d);
        float mn = fmaxf(m_run, mo);
        s_run = s_run * expf(m_run - mn) + so * expf(mo - mn);
        m_run = mn;
    }
    if (lane == 0) {
        rowmax[b * N_ + i] = m_run;
        rowsum[b * N_ + i] = s_run;
    }
}

// -------------------- per-batch softmax reduce: rowscale_i = exp(rmax_i-gmax)/total ----------
__global__ void k_gred(const float* __restrict__ rowmax, const float* __restrict__ rowsum,
                       float* __restrict__ rowscale) {
    int b = blockIdx.x, tid = threadIdx.x;   // 512
    __shared__ float mred[512], sred[512];
    float m = (tid < N_) ? rowmax[b * N_ + tid] : -1e30f;
    float s = (tid < N_) ? rowsum[b * N_ + tid] : 0.f;
    mred[tid] = m;
    __syncthreads();
    for (int st = 256; st > 0; st >>= 1) {
        if (tid < st) mred[tid] = fmaxf(mred[tid], mred[tid + st]);
        __syncthreads();
    }
    float gm = mred[0];
    sred[tid] = s * expf(m - gm);
    __syncthreads();
    for (int st = 256; st > 0; st >>= 1) {
        if (tid < st) sred[tid] += sred[tid + st];
        __syncthreads();
    }
    float inv = 1.f / sred[0];
    if (tid < N_) rowscale[b * N_ + tid] = expf(m - gm) * inv;
}

// -------------------- phase 2: x (algebraic LN, shuffle-reduce, coalesced att write) ----------
__global__ __launch_bounds__(256) void k_x(
    const float* __restrict__ inp, const float* __restrict__ pos,
    const float* __restrict__ coeffF, const float* __restrict__ scal,
    const float* __restrict__ vbeta, const float* __restrict__ vW2,
    const float* __restrict__ vb2, float* __restrict__ scoresAtt,
    const float* __restrict__ rowmax, const float* __restrict__ rowscale,
    float* __restrict__ xout) {
    int i = blockIdx.x, b = blockIdx.y;
    int tid = threadIdx.x;
    int lane = tid & 63, w = tid >> 6;
    int jsub = tid >> 3, dg = tid & 7;

    __shared__ float accHp[4 * 128];
    __shared__ float accIp[4 * 64];
    __shared__ float accSp[4];

    float cA[16], cB[16], cC[16], vB[16];
#pragma unroll
    for (int dd = 0; dd < 16; ++dd) {
        int d = dg * 16 + dd;
        cA[dd] = coeffF[d]; cB[dd] = coeffF[128 + d];
        cC[dd] = coeffF[256 + d]; vB[dd] = vbeta[d];
    }
    const float Saa = scal[0], Sbb = scal[1], Scc = scal[2];
    const float Sab = scal[3], Sac = scal[4], Sbc = scal[5];
    const float rmaxI = rowmax[b * N_ + i];
    const float rscaleI = rowscale[b * N_ + i];

    float aH[16];
    float aI[8];
#pragma unroll
    for (int dd = 0; dd < 16; ++dd) aH[dd] = 0.f;
#pragma unroll
    for (int ff = 0; ff < 8; ++ff) aI[ff] = 0.f;
    float aS = 0.f;

    const float* pi = pos + (size_t)(b * N_ + i) * 3;
    float ax = pi[0], ay = pi[1], az = pi[2];
    float* scoreRow = scoresAtt + (size_t)(b * N_ + i) * N_;

    for (int jc = 0; jc < 12; ++jc) {
        int j = jc * 32 + jsub;
        const float* pj = pos + (size_t)(b * N_ + j) * 3;
        float bx = pj[0], by = pj[1], bz = pj[2];
        float dotv = ax * bx + ay * by + az * bz;
        float cx = ay * bz - az * by;
        float cy = az * bx - ax * bz;
        float cz = ax * by - ay * bx;
        float cns = cx * cx + cy * cy + cz * cz;
        float cn = sqrtf(cns);

        float sc = scoreRow[j];
        float a = expf(sc - rmaxI) * rscaleI;

        float var = Saa * dotv * dotv + Sbb * cns + Scc +
                    2.f * (Sab * dotv * cn + Sac * dotv + Sbc * cn);
        float rstd = rsqrtf(var + LN_EPS);
        float dr = dotv * rstd, cr = cn * rstd;
#pragma unroll
        for (int dd = 0; dd < 16; ++dd) {
            float v = fmaf(dr, cA[dd], fmaf(cr, cB[dd], fmaf(rstd, cC[dd], vB[dd])));
            aH[dd] = fmaf(a, fmaxf(v, 0.f), aH[dd]);
        }
#pragma unroll
        for (int ff = 0; ff < 8; ++ff) {
            int f = dg * 8 + ff;
            aI[ff] = fmaf(a, inp[(size_t)(b * N_ + j) * F_ + f], aI[ff]);
        }
        if (dg == 0) aS += a;
    }

    // wave-level reduce over jsub (lane bits 3/4/5), dg preserved
#pragma unroll
    for (int m = 8; m <= 32; m <<= 1) {
#pragma unroll
        for (int dd = 0; dd < 16; ++dd) aH[dd] += __shfl_xor(aH[dd], m);
#pragma unroll
        for (int ff = 0; ff < 8; ++ff) aI[ff] += __shfl_xor(aI[ff], m);
        aS += __shfl_xor(aS, m);
    }
    if (lane < 8) {
#pragma unroll
        for (int dd = 0; dd < 16; ++dd) accHp[w * 128 + lane * 16 + dd] = aH[dd];
#pragma unroll
        for (int ff = 0; ff < 8; ++ff) accIp[w * 64 + lane * 8 + ff] = aI[ff];
        if (lane == 0) accSp[w] = aS;
    }
    __syncthreads();

    // coalesced att normalize pass (loop reads complete past the barrier)
    {
        float sc = scoreRow[tid];
        scoreRow[tid] = expf(sc - rmaxI) * rscaleI;
        if (tid < N_ - 256) {
            float sc2 = scoreRow[tid + 256];
            scoreRow[tid + 256] = expf(sc2 - rmaxI) * rscaleI;
        }
    }

    // combine 4 wave partials
    if (tid < 128) {
        accHp[tid] = accHp[tid] + accHp[128 + tid] + accHp[256 + tid] + accHp[384 + tid];
    } else if (tid < 192) {
        int f = tid - 128;
        accIp[f] = accIp[f] + accIp[64 + f] + accIp[128 + f] + accIp[192 + f];
    } else if (tid == 192) {
        accSp[0] = accSp[0] + accSp[1] + accSp[2] + accSp[3];
    }
    __syncthreads();

    if (tid < F_) {
        int f = tid;
        float s = accSp[0];
        float xv = 0.f;
#pragma unroll
        for (int d = 0; d < H_; ++d) xv = fmaf(accHp[d], vW2[d * F_ + f], xv);
        float r = 0.5f * (xv + s * vb2[f]) +
                  0.25f * (s * inp[(size_t)(b * N_ + i) * F_ + f] + accIp[f]);
        xout[(size_t)(b * N_ + i) * F_ + f] = r;
    }
}

// -------------------- launch --------------------

extern "C" void kernel_launch(void* const* d_in, const int* in_sizes, int n_in,
                              void* d_out, int out_size, void* d_ws, size_t ws_size,
                              hipStream_t stream) {
    const float* inp   = (const float*)d_in[0];
    const float* pos   = (const float*)d_in[1];
    const float* vW1   = (const float*)d_in[2];
    const float* vb1   = (const float*)d_in[3];
    const float* vg    = (const float*)d_in[4];
    const float* vbeta = (const float*)d_in[5];
    const float* vW2   = (const float*)d_in[6];
    const float* vb2   = (const float*)d_in[7];
    const float* sW1   = (const float*)d_in[8];
    const float* sb1   = (const float*)d_in[9];
    const float* sW2   = (const float*)d_in[10];
    const float* sb2   = (const float*)d_in[11];

    float* xout   = (float*)d_out;                 // B*N*F
    float* attout = xout + B_ * N_ * F_;           // B*N*N (scores -> att in place)

    unsigned short* W2hT   = (unsigned short*)d_ws;                  // 32KB fp16
    unsigned int*   coeffP = (unsigned int*)((char*)d_ws + 32768);   // 1KB packed f16x2
    float*          scal   = (float*)((char*)d_ws + 33792);          // 6 scalars (pad to 256B)
    float*          coeffF = (float*)((char*)d_ws + 34048);          // 3x128 fp32 (1.5KB)
    unsigned int*   sw16   = (unsigned int*)((char*)d_ws + 35584);   // 64 uints (256B)
    unsigned int*   t16    = (unsigned int*)((char*)d_ws + 35840);   // B*N*64 uints (768KB)
    float* rowmax   = (float*)((char*)d_ws + 35840 + B_ * N_ * 64 * 4);
    float* rowsum   = rowmax + B_ * N_;
    float* rowscale = rowsum + B_ * N_;

    k_prep<<<B_ * N_ + 128 + 1, 128, 0, stream>>>(
        inp, sW1, vb2, sb1, vW2, vW1, vb1, vg, vbeta, sW2,
        t16, W2hT, coeffP, scal, coeffF, sw16);
    k_scores<<<dim3(96, B_), 256, 0, stream>>>(
        pos, coeffP, scal, W2hT, t16, sw16, sb2, attout, rowmax, rowsum);
    k_gred<<<B_, 512, 0, stream>>>(rowmax, rowsum, rowscale);
    k_x<<<dim3(N_, B_), 256, 0, stream>>>(inp, pos, coeffF, scal, vbeta, vW2, vb2,
                                          attout, rowmax, rowscale, xout);
}

// Round 15
// 152.201 us; speedup vs baseline: 1.6257x; 1.1030x over previous
//
#include <hip/hip_runtime.h>
#include <hip/hip_bf16.h>
#include <math.h>

#define B_ 8
#define N_ 384
#define F_ 64
#define H_ 128
#define LN_EPS 1e-5f

typedef _Float16 f16;
typedef f16 f16x2 __attribute__((ext_vector_type(2)));
typedef f16 f16x4 __attribute__((ext_vector_type(4)));
typedef f16 f16x8 __attribute__((ext_vector_type(8)));
typedef float f32x4v __attribute__((ext_vector_type(4)));

static __device__ __forceinline__ f16x2 u2h(unsigned int u) {
    union { unsigned int u; f16x2 h; } c; c.u = u; return c.h;
}
static __device__ __forceinline__ unsigned int h2u(f16 a, f16 b) {
    union { f16x2 h; unsigned int u; } c; c.h = (f16x2){a, b}; return c.u;
}

// packed-permuted index helpers: uint slot u = h4*16 + mf*2 + p packs
// elements (n, n+1) with n = mf*16 + h4*4 + 2p  (matches MFMA C/D row layout)
static __device__ __forceinline__ void perm_idx(int m, int& u, int& n0) {
    int h4 = (m >> 1) & 3, mf = m >> 3, p = m & 1;
    u = h4 * 16 + mf * 2 + p;
    n0 = mf * 16 + h4 * 4 + 2 * p;
}

// -------------------- fused setup kernel --------------------
__global__ __launch_bounds__(128) void k_prep(
    const float* __restrict__ inp, const float* __restrict__ sW1,
    const float* __restrict__ vb2, const float* __restrict__ sb1,
    const float* __restrict__ vW2, const float* __restrict__ vW1,
    const float* __restrict__ vb1, const float* __restrict__ vg,
    const float* __restrict__ vbeta, const float* __restrict__ sW2,
    unsigned int* __restrict__ t16, unsigned short* __restrict__ W2hT,
    unsigned int* __restrict__ coeffP, float* __restrict__ scal,
    unsigned int* __restrict__ sw16) {
    __shared__ float red[128];
    __shared__ float caS[128], cbS[128], ccS[128];
    const int bx = blockIdx.x;
    const int tid = threadIdx.x;

    if (bx < B_ * N_) {
        // tt[n] = 0.25*(in[row]+vb2)@sW1[:,n] + 0.5*sb1[n] ; pack-permute to t16
        int row = bx, n = tid;
        float acc = 0.f;
#pragma unroll
        for (int f = 0; f < F_; ++f)
            acc = fmaf(0.25f * (inp[row * F_ + f] + vb2[f]), sW1[f * H_ + n], acc);
        red[n] = acc + 0.5f * sb1[n];
        __syncthreads();
        if (tid < 64) {
            int u, n0; perm_idx(tid, u, n0);
            t16[row * 64 + u] = h2u((f16)red[n0], (f16)red[n0 + 1]);
        }
        return;
    }
    if (bx < B_ * N_ + 128) {
        int idx = (bx - B_ * N_) * 128 + tid;
        int k = idx >> 7, n = idx & 127;
        float acc = 0.f;
#pragma unroll
        for (int f = 0; f < F_; ++f) acc = fmaf(vW2[k * F_ + f], sW1[f * H_ + n], acc);
        f16 hv = (f16)(0.5f * acc);
        W2hT[n * H_ + k] = *reinterpret_cast<unsigned short*>(&hv);
        return;
    }

    // ---- algebraic-LN coefficients + sw16 ----
    const int d = tid;   // 128
    float a = vW1[d], bb = vW1[H_ + d], c = vb1[d];
    float mA, mB, mC, Saa, Sbb, Scc, Sab, Sac, Sbc;
    float ca, cb, cc;
#define BMEAN(OUT, VAL)                                                  \
    red[d] = (VAL); __syncthreads();                                     \
    for (int st = 64; st > 0; st >>= 1) {                                \
        if (d < st) red[d] += red[d + st];                               \
        __syncthreads();                                                 \
    }                                                                    \
    OUT = red[0] * (1.f / 128.f); __syncthreads();

    BMEAN(mA, a); BMEAN(mB, bb); BMEAN(mC, c);
    ca = a - mA; cb = bb - mB; cc = c - mC;
    caS[d] = ca * vg[d]; cbS[d] = cb * vg[d]; ccS[d] = cc * vg[d];
    BMEAN(Saa, ca * ca); BMEAN(Sbb, cb * cb); BMEAN(Scc, cc * cc);
    BMEAN(Sab, ca * cb); BMEAN(Sac, ca * cc); BMEAN(Sbc, cb * cc);
#undef BMEAN
    __syncthreads();
    if (d < 64) {
        int d0 = 2 * d;
        coeffP[d]       = h2u((f16)caS[d0], (f16)caS[d0 + 1]);
        coeffP[64 + d]  = h2u((f16)cbS[d0], (f16)cbS[d0 + 1]);
        coeffP[128 + d] = h2u((f16)ccS[d0], (f16)ccS[d0 + 1]);
        coeffP[192 + d] = h2u((f16)vbeta[d0], (f16)vbeta[d0 + 1]);
        int u, n0; perm_idx(d, u, n0);
        sw16[u] = h2u((f16)sW2[n0], (f16)sW2[n0 + 1]);
    }
    if (d == 0) {
        scal[0] = Saa; scal[1] = Sbb; scal[2] = Scc;
        scal[3] = Sab; scal[4] = Sac; scal[5] = Sbc;
    }
}

// -------------------- phase 1: scores + flash accH of relu_h (x fused) --------------------
// R13 structure + flash accumulation. FIX vs R14: accH accumulates the VALUE-net
// hidden relu_h = bF (lane's dims kc*32+h4*8+e for pair ln), NOT relu(score-hidden).
// Epilogue: merge m over ln bits, single rescale, plain tree-sum of (s, accH);
// then accH@vW2 (fp32 LDS) -> xpart[row][64].
__global__ __launch_bounds__(256) void k_scores(
    const float* __restrict__ pos, const unsigned int* __restrict__ coeffP,
    const float* __restrict__ scal, const unsigned short* __restrict__ W2hT,
    const float* __restrict__ vW2, const unsigned int* __restrict__ t16,
    const unsigned int* __restrict__ sw16, const float* __restrict__ sb2,
    float* __restrict__ scores, float* __restrict__ rowmax,
    float* __restrict__ rowsum, float* __restrict__ xpart) {
    __shared__ __align__(16) char smem[65536];   // 32KB W' (swizzled) + 32KB vW2 fp32

    const int tid = threadIdx.x;
    const int b = blockIdx.y;
    const int w = tid >> 6, lane = tid & 63;
    const int i = blockIdx.x * 4 + w;
    const int ln = lane & 15, h4 = lane >> 4;

    // ---- one-time stage: W' swizzled + vW2 fp32 ----
#pragma unroll
    for (int s = 0; s < 8; ++s) {
        int idx = tid + s * 256;
        int n = idx >> 4, c = idx & 15;
        uint4 v = *(const uint4*)(W2hT + n * H_ + c * 8);
        *(uint4*)(smem + ((n * 256 + c * 16) ^ ((n & 7) << 4))) = v;
    }
#pragma unroll
    for (int s = 0; s < 8; ++s) {
        int idx = tid + s * 256;            // 0..2047 float4 chunks of vW2 (128x64)
        uint4 v = *(const uint4*)((const float*)vW2 + idx * 4);
        *(uint4*)(smem + 32768 + idx * 16) = v;
    }
    __syncthreads();

    // ---- resident state ----
    uint4 cagR[4], cbgR[4], ccgR[4], vbR[4];
#pragma unroll
    for (int kc = 0; kc < 4; ++kc) {
        cagR[kc] = *(const uint4*)(coeffP + kc * 16 + h4 * 4);
        cbgR[kc] = *(const uint4*)(coeffP + 64 + kc * 16 + h4 * 4);
        ccgR[kc] = *(const uint4*)(coeffP + 128 + kc * 16 + h4 * 4);
        vbR[kc]  = *(const uint4*)(coeffP + 192 + kc * 16 + h4 * 4);
    }
    unsigned int tih[16];
    {
        const unsigned int* tiP = t16 + (size_t)(b * N_ + i) * 64 + h4 * 16;
#pragma unroll
        for (int s = 0; s < 4; ++s) {
            uint4 v = *(const uint4*)(tiP + s * 4);
            tih[s * 4 + 0] = v.x; tih[s * 4 + 1] = v.y;
            tih[s * 4 + 2] = v.z; tih[s * 4 + 3] = v.w;
        }
    }
    uint2 swR[8];
#pragma unroll
    for (int mf = 0; mf < 8; ++mf)
        swR[mf] = *(const uint2*)(sw16 + h4 * 16 + mf * 2);

    const float Saa = scal[0], Sbb = scal[1], Scc = scal[2];
    const float Sab = scal[3], Sac = scal[4], Sbc = scal[5];
    const float sb2v = sb2[0];

    const float* pi = pos + (size_t)(b * N_ + i) * 3;
    const float ax = pi[0], ay = pi[1], az = pi[2];
    float* scoreRow = scores + (size_t)(b * N_ + i) * N_;

    float m_run = -1e30f, s_run = 0.f;
    float accH[4][8];
#pragma unroll
    for (int kc = 0; kc < 4; ++kc)
#pragma unroll
        for (int e = 0; e < 8; ++e) accH[kc][e] = 0.f;

    // pos prefetch for tile 0
    const float* pj0p = pos + (size_t)(b * N_ + ln) * 3;
    float bx = pj0p[0], by = pj0p[1], bz = pj0p[2];

#pragma unroll 1
    for (int jt = 0; jt < 24; ++jt) {
        const int j0 = jt * 16;

        // ---- tj prefetch (packed), consumed at phaseC ----
        const unsigned int* tjP = t16 + (size_t)(b * N_ + j0 + ln) * 64 + h4 * 16;
        uint4 tj0 = *(const uint4*)(tjP);
        uint4 tj1 = *(const uint4*)(tjP + 4);
        uint4 tj2 = *(const uint4*)(tjP + 8);
        uint4 tj3 = *(const uint4*)(tjP + 12);

        // ---- geometry ----
        float dotv = ax * bx + ay * by + az * bz;
        float cx = ay * bz - az * by;
        float cy = az * bx - ax * bz;
        float cz = ax * by - ay * bx;
        float cns = cx * cx + cy * cy + cz * cz;
        float cn = sqrtf(cns);

        // pos prefetch for next tile
        {
            int jn = (jt < 23) ? (j0 + 16) : j0;
            const float* pn = pos + (size_t)(b * N_ + jn + ln) * 3;
            bx = pn[0]; by = pn[1]; bz = pn[2];
        }

        float var = Saa * dotv * dotv + Sbb * cns + Scc +
                    2.f * (Sab * dotv * cn + Sac * dotv + Sbc * cn);
        float rstd = rsqrtf(var + LN_EPS);
        f16 d2 = (f16)(dotv * rstd), c2 = (f16)(cn * rstd), r2 = (f16)rstd;
        f16x2 D2 = {d2, d2}, C2 = {c2, c2}, R2 = {r2, r2};
        const f16x2 Z = {(f16)0.f, (f16)0.f};

        // ---- B-fragments (relu_h) in registers ----
        f16x8 bF[4];
#pragma unroll
        for (int kc = 0; kc < 4; ++kc) {
            f16x2 vp0 = __builtin_elementwise_max(D2 * u2h(cagR[kc].x) + (C2 * u2h(cbgR[kc].x) + (R2 * u2h(ccgR[kc].x) + u2h(vbR[kc].x))), Z);
            f16x2 vp1 = __builtin_elementwise_max(D2 * u2h(cagR[kc].y) + (C2 * u2h(cbgR[kc].y) + (R2 * u2h(ccgR[kc].y) + u2h(vbR[kc].y))), Z);
            f16x2 vp2 = __builtin_elementwise_max(D2 * u2h(cagR[kc].z) + (C2 * u2h(cbgR[kc].z) + (R2 * u2h(ccgR[kc].z) + u2h(vbR[kc].z))), Z);
            f16x2 vp3 = __builtin_elementwise_max(D2 * u2h(cagR[kc].w) + (C2 * u2h(cbgR[kc].w) + (R2 * u2h(ccgR[kc].w) + u2h(vbR[kc].w))), Z);
            f16x4 q01 = __builtin_shufflevector(vp0, vp1, 0, 1, 2, 3);
            f16x4 q23 = __builtin_shufflevector(vp2, vp3, 0, 1, 2, 3);
            bF[kc] = __builtin_shufflevector(q01, q23, 0, 1, 2, 3, 4, 5, 6, 7);
        }

        // ---- acc init = ti ----
        f32x4v acc[8];
#pragma unroll
        for (int mf = 0; mf < 8; ++mf) {
            f16x2 t0 = u2h(tih[mf * 2]);
            f16x2 t1 = u2h(tih[mf * 2 + 1]);
            acc[mf][0] = (float)t0[0]; acc[mf][1] = (float)t0[1];
            acc[mf][2] = (float)t1[0]; acc[mf][3] = (float)t1[1];
        }

        // ---- GEMM: A from LDS, B in regs ----
#pragma unroll
        for (int kc = 0; kc < 4; ++kc) {
            const int kb = (kc * 64 + h4 * 16) ^ ((ln & 7) << 4);
#pragma unroll
            for (int mf = 0; mf < 8; ++mf) {
                f16x8 aFr = *(const f16x8*)(smem + (mf * 16 + ln) * 256 + kb);
                acc[mf] = __builtin_amdgcn_mfma_f32_16x16x32_f16(aFr, bF[kc], acc[mf], 0, 0, 0);
            }
        }

        // ---- phaseC: relu(acc+tj) dot sw; reduce over h4 ----
        unsigned int tju[16] = {tj0.x, tj0.y, tj0.z, tj0.w, tj1.x, tj1.y, tj1.z, tj1.w,
                                tj2.x, tj2.y, tj2.z, tj2.w, tj3.x, tj3.y, tj3.z, tj3.w};
        float part = 0.f;
#pragma unroll
        for (int mf = 0; mf < 8; ++mf) {
            f16x2 s0 = u2h(swR[mf].x), s1 = u2h(swR[mf].y);
            f16x2 jh0 = u2h(tju[mf * 2]), jh1 = u2h(tju[mf * 2 + 1]);
            part += fmaxf(acc[mf][0] + (float)jh0[0], 0.f) * (float)s0[0];
            part += fmaxf(acc[mf][1] + (float)jh0[1], 0.f) * (float)s0[1];
            part += fmaxf(acc[mf][2] + (float)jh1[0], 0.f) * (float)s1[0];
            part += fmaxf(acc[mf][3] + (float)jh1[1], 0.f) * (float)s1[1];
        }
        part += __shfl_xor(part, 16);
        part += __shfl_xor(part, 32);
        float sc = part + sb2v;
        if (h4 == 0) scoreRow[j0 + ln] = sc;

        // ---- online stats + flash accH accumulate (of relu_h = bF) ----
        float mn = fmaxf(m_run, sc);
        float sca = expf(m_run - mn);    // 0 on first tile, 1 when no update
        float a = expf(sc - mn);
        if (mn > m_run) {
#pragma unroll
            for (int kc = 0; kc < 4; ++kc)
#pragma unroll
                for (int e = 0; e < 8; ++e) accH[kc][e] *= sca;
        }
        s_run = s_run * sca + a;
        m_run = mn;
#pragma unroll
        for (int kc = 0; kc < 4; ++kc)
#pragma unroll
            for (int e = 0; e < 8; ++e)
                accH[kc][e] = fmaf(a, (float)bF[kc][e], accH[kc][e]);
    }

    // ---- epilogue: merge over ln bits — max first, single rescale, tree sums ----
    float m_tot = m_run;
#pragma unroll
    for (int d = 1; d < 16; d <<= 1) m_tot = fmaxf(m_tot, __shfl_xor(m_tot, d));
    float fsc = expf(m_run - m_tot);
    s_run *= fsc;
#pragma unroll
    for (int kc = 0; kc < 4; ++kc)
#pragma unroll
        for (int e = 0; e < 8; ++e) accH[kc][e] *= fsc;
#pragma unroll
    for (int d = 1; d < 16; d <<= 1) {
        s_run += __shfl_xor(s_run, d);
#pragma unroll
        for (int kc = 0; kc < 4; ++kc)
#pragma unroll
            for (int e = 0; e < 8; ++e) accH[kc][e] += __shfl_xor(accH[kc][e], d);
    }
    if (lane == 0) {
        rowmax[b * N_ + i] = m_tot;
        rowsum[b * N_ + i] = s_run;
    }

    // ---- accH @ vW2 (fp32, LDS): lane (ln,h4) dims d=kc*32+h4*8+e -> f=ln*4..+3 ----
    float xp0 = 0.f, xp1 = 0.f, xp2 = 0.f, xp3 = 0.f;
#pragma unroll
    for (int kc = 0; kc < 4; ++kc) {
#pragma unroll
        for (int e = 0; e < 8; ++e) {
            int dIdx = kc * 32 + h4 * 8 + e;
            float av = accH[kc][e];
            float4 wv = *(const float4*)(smem + 32768 + dIdx * 256 + ln * 16);
            xp0 = fmaf(av, wv.x, xp0); xp1 = fmaf(av, wv.y, xp1);
            xp2 = fmaf(av, wv.z, xp2); xp3 = fmaf(av, wv.w, xp3);
        }
    }
    xp0 += __shfl_xor(xp0, 16); xp0 += __shfl_xor(xp0, 32);
    xp1 += __shfl_xor(xp1, 16); xp1 += __shfl_xor(xp1, 32);
    xp2 += __shfl_xor(xp2, 16); xp2 += __shfl_xor(xp2, 32);
    xp3 += __shfl_xor(xp3, 16); xp3 += __shfl_xor(xp3, 32);
    if (h4 == 0) {
        float4 o = {xp0, xp1, xp2, xp3};
        *(float4*)(xpart + (size_t)(b * N_ + i) * F_ + ln * 4) = o;
    }
}

// -------------------- per-batch softmax reduce: rowscale_i = exp(rmax_i-gmax)/total ----------
__global__ void k_gred(const float* __restrict__ rowmax, const float* __restrict__ rowsum,
                       float* __restrict__ rowscale) {
    int b = blockIdx.x, tid = threadIdx.x;   // 512
    __shared__ float mred[512], sred[512];
    float m = (tid < N_) ? rowmax[b * N_ + tid] : -1e30f;
    float s = (tid < N_) ? rowsum[b * N_ + tid] : 0.f;
    mred[tid] = m;
    __syncthreads();
    for (int st = 256; st > 0; st >>= 1) {
        if (tid < st) mred[tid] = fmaxf(mred[tid], mred[tid + st]);
        __syncthreads();
    }
    float gm = mred[0];
    sred[tid] = s * expf(m - gm);
    __syncthreads();
    for (int st = 256; st > 0; st >>= 1) {
        if (tid < st) sred[tid] += sred[tid + st];
        __syncthreads();
    }
    float inv = 1.f / sred[0];
    if (tid < N_) rowscale[b * N_ + tid] = expf(m - gm) * inv;
}

// -------------------- k_xlite: att normalize + accI + final combine --------------------
// x = 0.5*(xpart*rowscale + s*vb2) + 0.25*(s*in_i + att@inp), s = rowsum*rowscale
__global__ __launch_bounds__(256) void k_xlite(
    const float* __restrict__ inp, const float* __restrict__ vb2,
    float* __restrict__ scoresAtt, const float* __restrict__ rowmax,
    const float* __restrict__ rowsum, const float* __restrict__ rowscale,
    const float* __restrict__ xpart, float* __restrict__ xout) {
    int i = blockIdx.x, b = blockIdx.y;
    int tid = threadIdx.x;
    __shared__ float aLds[N_];
    __shared__ float accIp[256];

    const float rmaxI = rowmax[b * N_ + i];
    const float rscaleI = rowscale[b * N_ + i];
    float* scoreRow = scoresAtt + (size_t)(b * N_ + i) * N_;

    {
        float sc = scoreRow[tid];
        float a = expf(sc - rmaxI) * rscaleI;
        scoreRow[tid] = a; aLds[tid] = a;
        if (tid < N_ - 256) {
            float sc2 = scoreRow[tid + 256];
            float a2 = expf(sc2 - rmaxI) * rscaleI;
            scoreRow[tid + 256] = a2; aLds[tid + 256] = a2;
        }
    }
    __syncthreads();

    int f = tid & 63, q = tid >> 6;
    float aI = 0.f;
    const float* inB = inp + (size_t)b * N_ * F_;
    for (int j = q * 96; j < q * 96 + 96; ++j)
        aI = fmaf(aLds[j], inB[j * F_ + f], aI);
    accIp[tid] = aI;
    __syncthreads();

    if (tid < F_) {
        float accI = accIp[tid] + accIp[64 + tid] + accIp[128 + tid] + accIp[192 + tid];
        float s = rowsum[b * N_ + i] * rscaleI;
        float xp = xpart[(size_t)(b * N_ + i) * F_ + tid] * rscaleI;
        float r = 0.5f * (xp + s * vb2[tid]) +
                  0.25f * (s * inB[(size_t)i * F_ + tid] + accI);
        xout[(size_t)(b * N_ + i) * F_ + tid] = r;
    }
}

// -------------------- launch --------------------

extern "C" void kernel_launch(void* const* d_in, const int* in_sizes, int n_in,
                              void* d_out, int out_size, void* d_ws, size_t ws_size,
                              hipStream_t stream) {
    const float* inp   = (const float*)d_in[0];
    const float* pos   = (const float*)d_in[1];
    const float* vW1   = (const float*)d_in[2];
    const float* vb1   = (const float*)d_in[3];
    const float* vg    = (const float*)d_in[4];
    const float* vbeta = (const float*)d_in[5];
    const float* vW2   = (const float*)d_in[6];
    const float* vb2   = (const float*)d_in[7];
    const float* sW1   = (const float*)d_in[8];
    const float* sb1   = (const float*)d_in[9];
    const float* sW2   = (const float*)d_in[10];
    const float* sb2   = (const float*)d_in[11];

    float* xout   = (float*)d_out;                 // B*N*F
    float* attout = xout + B_ * N_ * F_;           // B*N*N (scores -> att in place)

    unsigned short* W2hT   = (unsigned short*)d_ws;                  // 32KB fp16
    unsigned int*   coeffP = (unsigned int*)((char*)d_ws + 32768);   // 1KB packed f16x2
    float*          scal   = (float*)((char*)d_ws + 33792);          // 6 scalars (pad)
    unsigned int*   sw16   = (unsigned int*)((char*)d_ws + 34048);   // 64 uints (256B)
    unsigned int*   t16    = (unsigned int*)((char*)d_ws + 34304);   // B*N*64 uints (768KB)
    float* rowmax   = (float*)((char*)d_ws + 34304 + B_ * N_ * 64 * 4);
    float* rowsum   = rowmax + B_ * N_;
    float* rowscale = rowsum + B_ * N_;
    float* xpart    = rowscale + B_ * N_;          // B*N*64 fp32 (768KB)

    k_prep<<<B_ * N_ + 128 + 1, 128, 0, stream>>>(
        inp, sW1, vb2, sb1, vW2, vW1, vb1, vg, vbeta, sW2,
        t16, W2hT, coeffP, scal, sw16);
    k_scores<<<dim3(96, B_), 256, 0, stream>>>(
        pos, coeffP, scal, W2hT, vW2, t16, sw16, sb2, attout, rowmax, rowsum, xpart);
    k_gred<<<B_, 512, 0, stream>>>(rowmax, rowsum, rowscale);
    k_xlite<<<dim3(N_, B_), 256, 0, stream>>>(inp, vb2, attout, rowmax, rowsum,
                                              rowscale, xpart, xout);
}